// Round 8
// baseline (218.110 us; speedup 1.0000x reference)
//
#include <hip/hip_runtime.h>

#define D_ 64
#define S_ 2048
#define B_ 16
#define QT 64
#define KVT 128

typedef short short8 __attribute__((ext_vector_type(8)));
typedef short short4a __attribute__((ext_vector_type(4)));
typedef float floatx4 __attribute__((ext_vector_type(4)));
typedef unsigned uint2v __attribute__((ext_vector_type(2)));

// exp(s/sqrt(2048)) == exp2(s * SC2); SC2 is pre-folded into the K pack.
#define SC2 (1.4426950408889634f / 45.254833995939045f)

__device__ __forceinline__ unsigned short f2bf(float f) {
  unsigned u = __builtin_bit_cast(unsigned, f);
  u += 0x7fffu + ((u >> 16) & 1u);   // round-to-nearest-even
  return (unsigned short)(u >> 16);
}

// 16x16x16 bf16 MFMA: B-operand k-mapping (k=4g+j) == C-layout m-mapping (m=4g+r),
// so the packed QK C-fragment feeds directly as the PV B-operand. A: m=ln, k=4g+j.
__device__ __forceinline__ floatx4 mfma16(short4a a, short4a b, floatx4 c) {
  return __builtin_amdgcn_mfma_f32_16x16x16bf16_1k(a, b, c, 0, 0, 0);
}

// ---------------------------------------------------------------------------
// pack_all: bid<128 -> Q [D][S][B]f32 -> [B][S][D]bf16
//           bid<256 -> K  same, pre-scaled by SC2
//           else    -> V -> [B][D][S]bf16 (transposed)
// ---------------------------------------------------------------------------
__global__ __launch_bounds__(256) void pack_all(const float* __restrict__ Q,
                                                const float* __restrict__ K,
                                                const float* __restrict__ V,
                                                unsigned short* __restrict__ Qp,
                                                unsigned short* __restrict__ Kp,
                                                unsigned short* __restrict__ Vt) {
  __shared__ __align__(16) unsigned short tile[256][72];
  const int t = threadIdx.x;
  const int bid = blockIdx.x;
  if (bid < 256) {
    const bool isK = bid >= 128;
    const float* src = isK ? K : Q;
    unsigned short* dst = isK ? Kp : Qp;
    const float scale = isK ? SC2 : 1.0f;
    const int s0 = (bid & 127) * 16;
#pragma unroll
    for (int i = 0; i < 16; i++) {
      int j = i * 256 + t;
      int d = j >> 6;
      int sb4 = (j & 63) * 4;
      const float4 v = *(const float4*)(src + (size_t)d * (S_ * B_) + s0 * B_ + sb4);
      float vv[4] = {v.x, v.y, v.z, v.w};
#pragma unroll
      for (int k = 0; k < 4; k++) {
        int sb = sb4 + k;                    // si = sb>>4, b = sb&15
        int row = (sb & 15) * 16 + (sb >> 4);
        int sw = (((row >> 3) & 1) << 3) | (((row >> 6) & 3) << 4);
        tile[row][d ^ sw] = f2bf(vv[k] * scale);
      }
    }
    __syncthreads();
#pragma unroll
    for (int i = 0; i < 8; i++) {
      int j = i * 256 + t;
      int r = j >> 3, c = j & 7;
      int b = r >> 4, si = r & 15;
      int sw = (((r >> 3) & 1) << 3) | (((r >> 6) & 3) << 4);
      uint4 v = *(const uint4*)(&tile[r][(c * 8) ^ sw]);
      *(uint4*)(dst + ((size_t)(b * S_ + s0 + si) * D_ + c * 8)) = v;
    }
  } else {
    const int vb = bid - 256;
    const int s0 = (vb & 31) * 64;
    const int d0 = (vb >> 5) * 16;
#pragma unroll
    for (int i = 0; i < 16; i++) {
      int j = i * 256 + t;
      int dd = j >> 8;
      int sb4 = (j & 255) * 4;
      const float4 v = *(const float4*)(V + (size_t)(d0 + dd) * (S_ * B_) + s0 * B_ + sb4);
      float vv[4] = {v.x, v.y, v.z, v.w};
#pragma unroll
      for (int k = 0; k < 4; k++) {
        int sb = sb4 + k;                    // si = sb>>4, b = sb&15
        int row = (sb & 15) * 16 + dd;
        int sw = ((row >> 6) & 3) << 3;
        tile[row][(sb >> 4) ^ sw] = f2bf(vv[k]);
      }
    }
    __syncthreads();
#pragma unroll
    for (int i = 0; i < 8; i++) {
      int j = i * 256 + t;
      int r = j >> 3, c = j & 7;
      int b = r >> 4, dd = r & 15;
      int sw = ((r >> 6) & 3) << 3;
      uint4 v = *(const uint4*)(&tile[r][(c * 8) ^ sw]);
      *(uint4*)(Vt + ((size_t)(b * D_ + d0 + dd) * S_ + s0 + c * 8)) = v;
    }
  }
}

// ---------------------------------------------------------------------------
// attn v4 (kv-split, occupancy 4 blocks/CU): grid 1024 = (kvh, qtile, batch).
// Each block handles one kv-HALF (8 tiles of 128) and writes UNNORMALIZED
// partial O^T + partial denominator; unpack combines the two halves.
// Single-buffered K/V LDS stage (35.8 KB) + 2-pass epilogue (36.9 KB alias)
// keeps LDS <= 40 KB; VGPR <= 128 -> 16 waves/CU (round-7 lesson: the 34 us
// attn was latency-bound at 8 waves/CU, pipes only ~25% loaded).
// ---------------------------------------------------------------------------
__global__ __launch_bounds__(256, 4) void attn(const unsigned short* __restrict__ Qp,
                                               const unsigned short* __restrict__ Kp,
                                               const unsigned short* __restrict__ Vt,
                                               float* __restrict__ Otp,
                                               float* __restrict__ Dp) {
  // stage: Ks[128*72] (18432 B) + Vs[64*136] (17408 B) = 35840 B
  // epilogue: red[4][64][36] f32 = 36864 B (aliases stage); lred separate 1 KB
  __shared__ __align__(16) char smem_[36864 + 1024];
  float* red = (float*)smem_;
  float* lred = (float*)(smem_ + 36864);

  const int tid = threadIdx.x;
  const int w = tid >> 6, l = tid & 63, g = l >> 4, ln = l & 15;
  const int b = blockIdx.x & 15;                      // XCD-pinned batch
  const int q0 = (int)((blockIdx.x >> 4) & 31) * QT;
  const int kvh = (int)(blockIdx.x >> 9);             // kv half: 0 or 1
  const int kvb = kvh << 10;
  const int kvw = w * 32;

  const unsigned short* Qb = Qp + (size_t)b * S_ * D_;
  const unsigned short* Kb = Kp + (size_t)b * S_ * D_;
  const unsigned short* Vb = Vt + (size_t)b * D_ * S_;

  const int rk = tid >> 3, ck = tid & 7;              // K stage coords
  const int rv = tid >> 4, cv = tid & 15;             // V stage coords

  // ---- stage tile 0 ----
  {
    unsigned short* Ks = (unsigned short*)smem_;
    unsigned short* Vs = (unsigned short*)(smem_ + 18432);
#pragma unroll
    for (int i = 0; i < 4; i++) {
      uint4 kv4 = *(const uint4*)(Kb + (size_t)(kvb + i * 32 + rk) * D_ + ck * 8);
      *(uint4*)(&Ks[(i * 32 + rk) * 72 + ck * 8]) = kv4;
      uint4 vv4 = *(const uint4*)(Vb + (size_t)(i * 16 + rv) * S_ + kvb + cv * 8);
      *(uint4*)(&Vs[(i * 16 + rv) * 136 + cv * 8]) = vv4;
    }
  }

  // Q^T B-frags, persistent: n=q=16nf+ln, k=d=32ks+8g+j
  short8 qf[4][2];
#pragma unroll
  for (int nf = 0; nf < 4; nf++)
#pragma unroll
    for (int ks = 0; ks < 2; ks++)
      qf[nf][ks] = *(const short8*)(Qb + (size_t)(q0 + nf * 16 + ln) * D_ + ks * 32 + g * 8);

  floatx4 oacc[4][4];                 // [d=16mfd+4g+r][q=16nf+ln], wave's kv partial
#pragma unroll
  for (int mfd = 0; mfd < 4; mfd++)
#pragma unroll
    for (int nf = 0; nf < 4; nf++) oacc[mfd][nf] = (floatx4){0.f, 0.f, 0.f, 0.f};
  float lpart[4] = {0.f, 0.f, 0.f, 0.f};

  __syncthreads();

  for (int t = 0; t < 8; t++) {
    unsigned short* Ks = (unsigned short*)smem_;
    unsigned short* Vs = (unsigned short*)(smem_ + 18432);
    const int kvn = kvb + (t + 1) * KVT;

    // ---- issue next tile's coalesced global loads (written after barrier1) ----
    uint4 kstg[4], vstg[4];
    if (t < 7) {
#pragma unroll
      for (int i = 0; i < 4; i++) {
        kstg[i] = *(const uint4*)(Kb + (size_t)(kvn + i * 32 + rk) * D_ + ck * 8);
        vstg[i] = *(const uint4*)(Vb + (size_t)(i * 16 + rv) * S_ + kvn + cv * 8);
      }
    }

    // ---- kf from LDS; S^T[32 kv][64 q] = K . Q^T (pre-scaled by SC2) ----
    short8 kf[2][2];
#pragma unroll
    for (int mf = 0; mf < 2; mf++)
#pragma unroll
      for (int ks = 0; ks < 2; ks++)
        kf[mf][ks] = *(const short8*)(&Ks[(kvw + mf * 16 + ln) * 72 + ks * 32 + g * 8]);
    floatx4 sacc[2][4];
#pragma unroll
    for (int mf = 0; mf < 2; mf++)
#pragma unroll
      for (int nf = 0; nf < 4; nf++) sacc[mf][nf] = (floatx4){0.f, 0.f, 0.f, 0.f};
#pragma unroll
    for (int ks = 0; ks < 2; ks++)
#pragma unroll
      for (int mf = 0; mf < 2; mf++)
#pragma unroll
        for (int nf = 0; nf < 4; nf++)
          sacc[mf][nf] = __builtin_amdgcn_mfma_f32_16x16x32_bf16(kf[mf][ks], qf[nf][ks],
                                                                 sacc[mf][nf], 0, 0, 0);

    // ---- P = exp2(sacc), packed in-register: C-frag -> B-frag ----
    short4a pb[2][4];
#pragma unroll
    for (int mf = 0; mf < 2; mf++)
#pragma unroll
      for (int nf = 0; nf < 4; nf++) {
        float p0 = __builtin_amdgcn_exp2f(sacc[mf][nf][0]);
        float p1 = __builtin_amdgcn_exp2f(sacc[mf][nf][1]);
        float p2 = __builtin_amdgcn_exp2f(sacc[mf][nf][2]);
        float p3 = __builtin_amdgcn_exp2f(sacc[mf][nf][3]);
        lpart[nf] += (p0 + p1) + (p2 + p3);
        unsigned u0 = __builtin_bit_cast(unsigned, p0) + 0x8000u;
        unsigned u1 = __builtin_bit_cast(unsigned, p1) + 0x8000u;
        unsigned u2 = __builtin_bit_cast(unsigned, p2) + 0x8000u;
        unsigned u3 = __builtin_bit_cast(unsigned, p3) + 0x8000u;
        unsigned lo = __builtin_amdgcn_perm(u1, u0, 0x07060302u);
        unsigned hi = __builtin_amdgcn_perm(u3, u2, 0x07060302u);
        pb[mf][nf] = __builtin_bit_cast(short4a, (uint2v){lo, hi});
      }

    // ---- vf from LDS; O^T += V^T . P^T over the wave's 32 kv ----
#pragma unroll
    for (int mfd = 0; mfd < 4; mfd++)
#pragma unroll
      for (int mf = 0; mf < 2; mf++) {
        short4a vf = *(const short4a*)(&Vs[(mfd * 16 + ln) * 136 + kvw + mf * 16 + g * 4]);
#pragma unroll
        for (int nf = 0; nf < 4; nf++)
          oacc[mfd][nf] = mfma16(vf, pb[mf][nf], oacc[mfd][nf]);
      }

    __syncthreads();   // barrier1: all waves done reading tile t
    if (t < 7) {
#pragma unroll
      for (int i = 0; i < 4; i++) {
        *(uint4*)(&Ks[(i * 32 + rk) * 72 + ck * 8]) = kstg[i];
        *(uint4*)(&Vs[(i * 16 + rv) * 136 + cv * 8]) = vstg[i];
      }
      __syncthreads();  // barrier2: tile t+1 staged
    }
  }

  // ---- epilogue: cross-wave partial-O reduction, 2 passes of d32 ----
  float lsum[4];
#pragma unroll
  for (int nf = 0; nf < 4; nf++) {
    float v = lpart[nf];
    v += __shfl_xor(v, 16);
    v += __shfl_xor(v, 32);
    lsum[nf] = v;
  }
  if (g == 0) {
#pragma unroll
    for (int nf = 0; nf < 4; nf++) lred[w * 64 + nf * 16 + ln] = lsum[nf];
  }
  const size_t oofs = (size_t)kvh * (B_ * D_ * S_);

  // pass 0: d in [0,32)  (mfd 0,1)
#pragma unroll
  for (int mfd = 0; mfd < 2; mfd++)
#pragma unroll
    for (int nf = 0; nf < 4; nf++)
      *(floatx4*)(&red[w * 2304 + (nf * 16 + ln) * 36 + mfd * 16 + g * 4]) = oacc[mfd][nf];
  __syncthreads();
  const int q = l;
  const float denom = lred[q] + lred[64 + q] + lred[128 + q] + lred[192 + q];
  if (w == 0) Dp[(size_t)kvh * (B_ * S_) + b * S_ + q0 + q] = denom;
#pragma unroll
  for (int i = 0; i < 2; i++) {
    floatx4 s = (floatx4){0.f, 0.f, 0.f, 0.f};
#pragma unroll
    for (int w2 = 0; w2 < 4; w2++)
      s += *(const floatx4*)(&red[w2 * 2304 + q * 36 + w * 8 + i * 4]);
    const int d = w * 8 + i * 4;
#pragma unroll
    for (int r = 0; r < 4; r++)
      Otp[oofs + (size_t)(b * D_ + d + r) * S_ + q0 + q] = s[r];
  }
  __syncthreads();

  // pass 1: d in [32,64)  (mfd 2,3)
#pragma unroll
  for (int mfd = 2; mfd < 4; mfd++)
#pragma unroll
    for (int nf = 0; nf < 4; nf++)
      *(floatx4*)(&red[w * 2304 + (nf * 16 + ln) * 36 + (mfd - 2) * 16 + g * 4]) = oacc[mfd][nf];
  __syncthreads();
#pragma unroll
  for (int i = 0; i < 2; i++) {
    floatx4 s = (floatx4){0.f, 0.f, 0.f, 0.f};
#pragma unroll
    for (int w2 = 0; w2 < 4; w2++)
      s += *(const floatx4*)(&red[w2 * 2304 + q * 36 + w * 8 + i * 4]);
    const int d = 32 + w * 8 + i * 4;
#pragma unroll
    for (int r = 0; r < 4; r++)
      Otp[oofs + (size_t)(b * D_ + d + r) * S_ + q0 + q] = s[r];
  }
}

// ---------------------------------------------------------------------------
// Unpack v2: out[d][s][b] = (O0+O1)[b][d][s] / (l0+l1)[b][s].
// Tile: 8 d x 64 s x 16 b; LDS word-swizzle as before (verified r3-r7).
// ---------------------------------------------------------------------------
__global__ __launch_bounds__(256) void unpack_o(const float* __restrict__ Otp,
                                                const float* __restrict__ Dp,
                                                float* __restrict__ out) {
  const int d0 = (int)(blockIdx.x & 7) * 8;
  const int s0 = (int)(blockIdx.x >> 3) * 64;
  __shared__ float u[8 * 1024];
  __shared__ float dinv[16 * 64];    // [bb][si]
  const int t = threadIdx.x;
  {
    int bb = t >> 4, si4 = (t & 15) * 4;
    float4 a = *(const float4*)(Dp + bb * S_ + s0 + si4);
    float4 c = *(const float4*)(Dp + (B_ * S_) + bb * S_ + s0 + si4);
    dinv[bb * 64 + si4 + 0] = 1.0f / (a.x + c.x);
    dinv[bb * 64 + si4 + 1] = 1.0f / (a.y + c.y);
    dinv[bb * 64 + si4 + 2] = 1.0f / (a.z + c.z);
    dinv[bb * 64 + si4 + 3] = 1.0f / (a.w + c.w);
  }
  __syncthreads();
#pragma unroll
  for (int i = 0; i < 8; i++) {
    int j = i * 256 + t;
    int d = j >> 8, bb = (j >> 4) & 15, c = j & 15;
    const float* p0 = Otp + (size_t)(bb * D_ + d0 + d) * S_ + s0 + c * 4;
    float4 v0 = *(const float4*)p0;
    float4 v1 = *(const float4*)(p0 + (size_t)B_ * D_ * S_);
    float vv[4] = {v0.x + v1.x, v0.y + v1.y, v0.z + v1.z, v0.w + v1.w};
#pragma unroll
    for (int k = 0; k < 4; k++) {
      int si = c * 4 + k;
      float val = vv[k] * dinv[bb * 64 + si];
      int W = si * 16 + bb;
      int Wp = W ^ ((si & 15) << 2);
      u[d * 1024 + Wp] = val;
    }
  }
  __syncthreads();
#pragma unroll
  for (int i = 0; i < 8; i++) {
    int j = i * 256 + t;
    int d = j >> 8, c2 = j & 255;
    int G = c2 ^ ((c2 >> 2) & 15);
    float4 v = *(const float4*)(&u[d * 1024 + G * 4]);
    *(float4*)(out + (size_t)(d0 + d) * (S_ * B_) + s0 * B_ + c2 * 4) = v;
  }
}

// ---------------------------------------------------------------------------
extern "C" void kernel_launch(void* const* d_in, const int* in_sizes, int n_in,
                              void* d_out, int out_size, void* d_ws, size_t ws_size,
                              hipStream_t stream) {
  const float* Q = (const float*)d_in[0];    // f32 [D][S][B]
  const float* K = (const float*)d_in[1];
  const float* V = (const float*)d_in[2];
  float* out = (float*)d_out;                // f32 [D][S][B]
  char* ws = (char*)d_ws;
  unsigned short* Qp = (unsigned short*)(ws);                  // 4 MB bf16 [B][S][D]
  unsigned short* Kp = (unsigned short*)(ws + (4u << 20));     // 4 MB bf16 [B][S][D], pre-scaled
  unsigned short* Vt = (unsigned short*)(ws + (8u << 20));     // 4 MB bf16 [B][D][S]
  float* Otp = (float*)(ws + (12u << 20));                     // 16 MB f32 [2][B][D][S] partials
  float* Dp  = (float*)(ws + (28u << 20));                     // 256 KB f32 [2][B][S] denom partials

  hipLaunchKernelGGL(pack_all, dim3(384), dim3(256), 0, stream, Q, K, V, Qp, Kp, Vt);
  hipLaunchKernelGGL(attn, dim3(1024), dim3(256), 0, stream, Qp, Kp, Vt, Otp, Dp);
  hipLaunchKernelGGL(unpack_o, dim3(256), dim3(256), 0, stream, Otp, Dp, out);
}

// Round 9
// 126.539 us; speedup vs baseline: 1.7237x; 1.7237x over previous
//
#include <hip/hip_runtime.h>

#define D_ 64
#define S_ 2048
#define B_ 16
#define QT 64
#define KVT 128

typedef short short8 __attribute__((ext_vector_type(8)));
typedef short short4a __attribute__((ext_vector_type(4)));
typedef float floatx4 __attribute__((ext_vector_type(4)));
typedef unsigned uint2v __attribute__((ext_vector_type(2)));

// exp(s/sqrt(2048)) == exp2(s * SC2); SC2 is pre-folded into the K pack.
#define SC2 (1.4426950408889634f / 45.254833995939045f)

__device__ __forceinline__ unsigned short f2bf(float f) {
  unsigned u = __builtin_bit_cast(unsigned, f);
  u += 0x7fffu + ((u >> 16) & 1u);   // round-to-nearest-even
  return (unsigned short)(u >> 16);
}

// 16x16x16 bf16 MFMA: B-operand k-mapping (k=4g+j) == C-layout m-mapping (m=4g+r),
// so the packed QK C-fragment feeds directly as the PV B-operand. A: m=ln, k=4g+j.
__device__ __forceinline__ floatx4 mfma16(short4a a, short4a b, floatx4 c) {
  return __builtin_amdgcn_mfma_f32_16x16x16bf16_1k(a, b, c, 0, 0, 0);
}

// ---------------------------------------------------------------------------
// pack_all: bid<128 -> Q [D][S][B]f32 -> [B][S][D]bf16
//           bid<256 -> K  same, pre-scaled by SC2
//           else    -> V -> [B][D][S]bf16 (transposed)
// ---------------------------------------------------------------------------
__global__ __launch_bounds__(256) void pack_all(const float* __restrict__ Q,
                                                const float* __restrict__ K,
                                                const float* __restrict__ V,
                                                unsigned short* __restrict__ Qp,
                                                unsigned short* __restrict__ Kp,
                                                unsigned short* __restrict__ Vt) {
  __shared__ __align__(16) unsigned short tile[256][72];
  const int t = threadIdx.x;
  const int bid = blockIdx.x;
  if (bid < 256) {
    const bool isK = bid >= 128;
    const float* src = isK ? K : Q;
    unsigned short* dst = isK ? Kp : Qp;
    const float scale = isK ? SC2 : 1.0f;
    const int s0 = (bid & 127) * 16;
#pragma unroll
    for (int i = 0; i < 16; i++) {
      int j = i * 256 + t;
      int d = j >> 6;
      int sb4 = (j & 63) * 4;
      const float4 v = *(const float4*)(src + (size_t)d * (S_ * B_) + s0 * B_ + sb4);
      float vv[4] = {v.x, v.y, v.z, v.w};
#pragma unroll
      for (int k = 0; k < 4; k++) {
        int sb = sb4 + k;                    // si = sb>>4, b = sb&15
        int row = (sb & 15) * 16 + (sb >> 4);
        int sw = (((row >> 3) & 1) << 3) | (((row >> 6) & 3) << 4);
        tile[row][d ^ sw] = f2bf(vv[k] * scale);
      }
    }
    __syncthreads();
#pragma unroll
    for (int i = 0; i < 8; i++) {
      int j = i * 256 + t;
      int r = j >> 3, c = j & 7;
      int b = r >> 4, si = r & 15;
      int sw = (((r >> 3) & 1) << 3) | (((r >> 6) & 3) << 4);
      uint4 v = *(const uint4*)(&tile[r][(c * 8) ^ sw]);
      *(uint4*)(dst + ((size_t)(b * S_ + s0 + si) * D_ + c * 8)) = v;
    }
  } else {
    const int vb = bid - 256;
    const int s0 = (vb & 31) * 64;
    const int d0 = (vb >> 5) * 16;
#pragma unroll
    for (int i = 0; i < 16; i++) {
      int j = i * 256 + t;
      int dd = j >> 8;
      int sb4 = (j & 255) * 4;
      const float4 v = *(const float4*)(V + (size_t)(d0 + dd) * (S_ * B_) + s0 * B_ + sb4);
      float vv[4] = {v.x, v.y, v.z, v.w};
#pragma unroll
      for (int k = 0; k < 4; k++) {
        int sb = sb4 + k;                    // si = sb>>4, b = sb&15
        int row = (sb & 15) * 16 + dd;
        int sw = ((row >> 6) & 3) << 3;
        tile[row][(sb >> 4) ^ sw] = f2bf(vv[k]);
      }
    }
    __syncthreads();
#pragma unroll
    for (int i = 0; i < 8; i++) {
      int j = i * 256 + t;
      int r = j >> 3, c = j & 7;
      int b = r >> 4, dd = r & 15;
      int sw = ((r >> 6) & 3) << 3;
      uint4 v = *(const uint4*)(&tile[r][(c * 8) ^ sw]);
      *(uint4*)(Vt + ((size_t)(b * D_ + d0 + dd) * S_ + s0 + c * 8)) = v;
    }
  }
}

// ---------------------------------------------------------------------------
// attn v5 (kv-split, 3 blocks/CU, NO spills): grid 1024 = (kvh, qtile, batch).
// Round-8 lesson: __launch_bounds__(256,4) capped VGPRs at 128 < ~190 live ->
// scratch spills (FETCH 6->285 MB) ate the occupancy win. This round:
//  - __launch_bounds__(256,3): cap ~170 >= ~156 compute-phase live set.
//  - staging registers removed from the live set: tile t+1 is copied
//    global->LDS AFTER barrier1 (transient regs only), not prefetched across
//    the compute phase. Exposed ~600cyc L2 latency/tile is covered by the
//    12 waves/CU of TLP this enables (r7 had 8 waves/CU and attn=34us).
// Single-buffered K/V stage (35.8 KB) + 2-pass epilogue; LDS block 37.9 KB.
// ---------------------------------------------------------------------------
__global__ __launch_bounds__(256, 3) void attn(const unsigned short* __restrict__ Qp,
                                               const unsigned short* __restrict__ Kp,
                                               const unsigned short* __restrict__ Vt,
                                               float* __restrict__ Otp,
                                               float* __restrict__ Dp) {
  // stage: Ks[128*72] (18432 B) + Vs[64*136] (17408 B) = 35840 B
  // epilogue: red[4][64][36] f32 = 36864 B (aliases stage); lred separate 1 KB
  __shared__ __align__(16) char smem_[36864 + 1024];
  float* red = (float*)smem_;
  float* lred = (float*)(smem_ + 36864);

  const int tid = threadIdx.x;
  const int w = tid >> 6, l = tid & 63, g = l >> 4, ln = l & 15;
  const int b = blockIdx.x & 15;                      // XCD-pinned batch
  const int q0 = (int)((blockIdx.x >> 4) & 31) * QT;
  const int kvh = (int)(blockIdx.x >> 9);             // kv half: 0 or 1
  const int kvb = kvh << 10;
  const int kvw = w * 32;

  const unsigned short* Qb = Qp + (size_t)b * S_ * D_;
  const unsigned short* Kb = Kp + (size_t)b * S_ * D_;
  const unsigned short* Vb = Vt + (size_t)b * D_ * S_;

  const int rk = tid >> 3, ck = tid & 7;              // K stage coords
  const int rv = tid >> 4, cv = tid & 15;             // V stage coords

  // ---- stage tile 0 (direct global->LDS copy) ----
  {
    unsigned short* Ks = (unsigned short*)smem_;
    unsigned short* Vs = (unsigned short*)(smem_ + 18432);
#pragma unroll
    for (int i = 0; i < 4; i++) {
      *(uint4*)(&Ks[(i * 32 + rk) * 72 + ck * 8]) =
          *(const uint4*)(Kb + (size_t)(kvb + i * 32 + rk) * D_ + ck * 8);
      *(uint4*)(&Vs[(i * 16 + rv) * 136 + cv * 8]) =
          *(const uint4*)(Vb + (size_t)(i * 16 + rv) * S_ + kvb + cv * 8);
    }
  }

  // Q^T B-frags, persistent: n=q=16nf+ln, k=d=32ks+8g+j
  short8 qf[4][2];
#pragma unroll
  for (int nf = 0; nf < 4; nf++)
#pragma unroll
    for (int ks = 0; ks < 2; ks++)
      qf[nf][ks] = *(const short8*)(Qb + (size_t)(q0 + nf * 16 + ln) * D_ + ks * 32 + g * 8);

  floatx4 oacc[4][4];                 // [d=16mfd+4g+r][q=16nf+ln], wave's kv partial
#pragma unroll
  for (int mfd = 0; mfd < 4; mfd++)
#pragma unroll
    for (int nf = 0; nf < 4; nf++) oacc[mfd][nf] = (floatx4){0.f, 0.f, 0.f, 0.f};
  float lpart[4] = {0.f, 0.f, 0.f, 0.f};

  __syncthreads();

  for (int t = 0; t < 8; t++) {
    unsigned short* Ks = (unsigned short*)smem_;
    unsigned short* Vs = (unsigned short*)(smem_ + 18432);

    // ---- kf from LDS; S^T[32 kv][64 q] = K . Q^T (pre-scaled by SC2) ----
    short8 kf[2][2];
#pragma unroll
    for (int mf = 0; mf < 2; mf++)
#pragma unroll
      for (int ks = 0; ks < 2; ks++)
        kf[mf][ks] = *(const short8*)(&Ks[(kvw + mf * 16 + ln) * 72 + ks * 32 + g * 8]);
    floatx4 sacc[2][4];
#pragma unroll
    for (int mf = 0; mf < 2; mf++)
#pragma unroll
      for (int nf = 0; nf < 4; nf++) sacc[mf][nf] = (floatx4){0.f, 0.f, 0.f, 0.f};
#pragma unroll
    for (int ks = 0; ks < 2; ks++)
#pragma unroll
      for (int mf = 0; mf < 2; mf++)
#pragma unroll
        for (int nf = 0; nf < 4; nf++)
          sacc[mf][nf] = __builtin_amdgcn_mfma_f32_16x16x32_bf16(kf[mf][ks], qf[nf][ks],
                                                                 sacc[mf][nf], 0, 0, 0);

    // ---- P = exp2(sacc), packed in-register: C-frag -> B-frag ----
    short4a pb[2][4];
#pragma unroll
    for (int mf = 0; mf < 2; mf++)
#pragma unroll
      for (int nf = 0; nf < 4; nf++) {
        float p0 = __builtin_amdgcn_exp2f(sacc[mf][nf][0]);
        float p1 = __builtin_amdgcn_exp2f(sacc[mf][nf][1]);
        float p2 = __builtin_amdgcn_exp2f(sacc[mf][nf][2]);
        float p3 = __builtin_amdgcn_exp2f(sacc[mf][nf][3]);
        lpart[nf] += (p0 + p1) + (p2 + p3);
        unsigned u0 = __builtin_bit_cast(unsigned, p0) + 0x8000u;
        unsigned u1 = __builtin_bit_cast(unsigned, p1) + 0x8000u;
        unsigned u2 = __builtin_bit_cast(unsigned, p2) + 0x8000u;
        unsigned u3 = __builtin_bit_cast(unsigned, p3) + 0x8000u;
        unsigned lo = __builtin_amdgcn_perm(u1, u0, 0x07060302u);
        unsigned hi = __builtin_amdgcn_perm(u3, u2, 0x07060302u);
        pb[mf][nf] = __builtin_bit_cast(short4a, (uint2v){lo, hi});
      }

    // ---- vf from LDS; O^T += V^T . P^T over the wave's 32 kv ----
#pragma unroll
    for (int mfd = 0; mfd < 4; mfd++)
#pragma unroll
      for (int mf = 0; mf < 2; mf++) {
        short4a vf = *(const short4a*)(&Vs[(mfd * 16 + ln) * 136 + kvw + mf * 16 + g * 4]);
#pragma unroll
        for (int nf = 0; nf < 4; nf++)
          oacc[mfd][nf] = mfma16(vf, pb[mf][nf], oacc[mfd][nf]);
      }

    __syncthreads();   // barrier1: all waves done reading tile t
    if (t < 7) {
      // ---- stage tile t+1 directly (transient regs only, not live across
      //      the compute phase -> no VGPR-cap spills) ----
      const int kvn = kvb + (t + 1) * KVT;
#pragma unroll
      for (int i = 0; i < 4; i++) {
        *(uint4*)(&Ks[(i * 32 + rk) * 72 + ck * 8]) =
            *(const uint4*)(Kb + (size_t)(kvn + i * 32 + rk) * D_ + ck * 8);
        *(uint4*)(&Vs[(i * 16 + rv) * 136 + cv * 8]) =
            *(const uint4*)(Vb + (size_t)(i * 16 + rv) * S_ + kvn + cv * 8);
      }
      __syncthreads();  // barrier2: tile t+1 staged
    }
  }

  // ---- epilogue: cross-wave partial-O reduction, 2 passes of d32 ----
  float lsum[4];
#pragma unroll
  for (int nf = 0; nf < 4; nf++) {
    float v = lpart[nf];
    v += __shfl_xor(v, 16);
    v += __shfl_xor(v, 32);
    lsum[nf] = v;
  }
  if (g == 0) {
#pragma unroll
    for (int nf = 0; nf < 4; nf++) lred[w * 64 + nf * 16 + ln] = lsum[nf];
  }
  const size_t oofs = (size_t)kvh * (B_ * D_ * S_);

  // pass 0: d in [0,32)  (mfd 0,1)
#pragma unroll
  for (int mfd = 0; mfd < 2; mfd++)
#pragma unroll
    for (int nf = 0; nf < 4; nf++)
      *(floatx4*)(&red[w * 2304 + (nf * 16 + ln) * 36 + mfd * 16 + g * 4]) = oacc[mfd][nf];
  __syncthreads();
  const int q = l;
  const float denom = lred[q] + lred[64 + q] + lred[128 + q] + lred[192 + q];
  if (w == 0) Dp[(size_t)kvh * (B_ * S_) + b * S_ + q0 + q] = denom;
#pragma unroll
  for (int i = 0; i < 2; i++) {
    floatx4 s = (floatx4){0.f, 0.f, 0.f, 0.f};
#pragma unroll
    for (int w2 = 0; w2 < 4; w2++)
      s += *(const floatx4*)(&red[w2 * 2304 + q * 36 + w * 8 + i * 4]);
    const int d = w * 8 + i * 4;
#pragma unroll
    for (int r = 0; r < 4; r++)
      Otp[oofs + (size_t)(b * D_ + d + r) * S_ + q0 + q] = s[r];
  }
  __syncthreads();

  // pass 1: d in [32,64)  (mfd 2,3)
#pragma unroll
  for (int mfd = 2; mfd < 4; mfd++)
#pragma unroll
    for (int nf = 0; nf < 4; nf++)
      *(floatx4*)(&red[w * 2304 + (nf * 16 + ln) * 36 + (mfd - 2) * 16 + g * 4]) = oacc[mfd][nf];
  __syncthreads();
#pragma unroll
  for (int i = 0; i < 2; i++) {
    floatx4 s = (floatx4){0.f, 0.f, 0.f, 0.f};
#pragma unroll
    for (int w2 = 0; w2 < 4; w2++)
      s += *(const floatx4*)(&red[w2 * 2304 + q * 36 + w * 8 + i * 4]);
    const int d = 32 + w * 8 + i * 4;
#pragma unroll
    for (int r = 0; r < 4; r++)
      Otp[oofs + (size_t)(b * D_ + d + r) * S_ + q0 + q] = s[r];
  }
}

// ---------------------------------------------------------------------------
// Unpack v2: out[d][s][b] = (O0+O1)[b][d][s] / (l0+l1)[b][s].
// Tile: 8 d x 64 s x 16 b; LDS word-swizzle as before (verified r3-r8).
// ---------------------------------------------------------------------------
__global__ __launch_bounds__(256) void unpack_o(const float* __restrict__ Otp,
                                                const float* __restrict__ Dp,
                                                float* __restrict__ out) {
  const int d0 = (int)(blockIdx.x & 7) * 8;
  const int s0 = (int)(blockIdx.x >> 3) * 64;
  __shared__ float u[8 * 1024];
  __shared__ float dinv[16 * 64];    // [bb][si]
  const int t = threadIdx.x;
  {
    int bb = t >> 4, si4 = (t & 15) * 4;
    float4 a = *(const float4*)(Dp + bb * S_ + s0 + si4);
    float4 c = *(const float4*)(Dp + (B_ * S_) + bb * S_ + s0 + si4);
    dinv[bb * 64 + si4 + 0] = 1.0f / (a.x + c.x);
    dinv[bb * 64 + si4 + 1] = 1.0f / (a.y + c.y);
    dinv[bb * 64 + si4 + 2] = 1.0f / (a.z + c.z);
    dinv[bb * 64 + si4 + 3] = 1.0f / (a.w + c.w);
  }
  __syncthreads();
#pragma unroll
  for (int i = 0; i < 8; i++) {
    int j = i * 256 + t;
    int d = j >> 8, bb = (j >> 4) & 15, c = j & 15;
    const float* p0 = Otp + (size_t)(bb * D_ + d0 + d) * S_ + s0 + c * 4;
    float4 v0 = *(const float4*)p0;
    float4 v1 = *(const float4*)(p0 + (size_t)B_ * D_ * S_);
    float vv[4] = {v0.x + v1.x, v0.y + v1.y, v0.z + v1.z, v0.w + v1.w};
#pragma unroll
    for (int k = 0; k < 4; k++) {
      int si = c * 4 + k;
      float val = vv[k] * dinv[bb * 64 + si];
      int W = si * 16 + bb;
      int Wp = W ^ ((si & 15) << 2);
      u[d * 1024 + Wp] = val;
    }
  }
  __syncthreads();
#pragma unroll
  for (int i = 0; i < 8; i++) {
    int j = i * 256 + t;
    int d = j >> 8, c2 = j & 255;
    int G = c2 ^ ((c2 >> 2) & 15);
    float4 v = *(const float4*)(&u[d * 1024 + G * 4]);
    *(float4*)(out + (size_t)(d0 + d) * (S_ * B_) + s0 * B_ + c2 * 4) = v;
  }
}

// ---------------------------------------------------------------------------
extern "C" void kernel_launch(void* const* d_in, const int* in_sizes, int n_in,
                              void* d_out, int out_size, void* d_ws, size_t ws_size,
                              hipStream_t stream) {
  const float* Q = (const float*)d_in[0];    // f32 [D][S][B]
  const float* K = (const float*)d_in[1];
  const float* V = (const float*)d_in[2];
  float* out = (float*)d_out;                // f32 [D][S][B]
  char* ws = (char*)d_ws;
  unsigned short* Qp = (unsigned short*)(ws);                  // 4 MB bf16 [B][S][D]
  unsigned short* Kp = (unsigned short*)(ws + (4u << 20));     // 4 MB bf16 [B][S][D], pre-scaled
  unsigned short* Vt = (unsigned short*)(ws + (8u << 20));     // 4 MB bf16 [B][D][S]
  float* Otp = (float*)(ws + (12u << 20));                     // 16 MB f32 [2][B][D][S] partials
  float* Dp  = (float*)(ws + (28u << 20));                     // 256 KB f32 [2][B][S] denom partials

  hipLaunchKernelGGL(pack_all, dim3(384), dim3(256), 0, stream, Q, K, V, Qp, Kp, Vt);
  hipLaunchKernelGGL(attn, dim3(1024), dim3(256), 0, stream, Qp, Kp, Vt, Otp, Dp);
  hipLaunchKernelGGL(unpack_o, dim3(256), dim3(256), 0, stream, Otp, Dp, out);
}